// Round 9
// baseline (1027.548 us; speedup 1.0000x reference)
//
#include <hip/hip_runtime.h>
#include <hip/hip_bf16.h>
#include <cstdint>
#include <cstddef>

#define NFEAT 512
#define H2 256
#define H3 256
#define H4 128
#define NCLASS 16

typedef __attribute__((ext_vector_type(8))) short short8;
typedef __attribute__((ext_vector_type(4))) float f32x4;
typedef __attribute__((ext_vector_type(4))) unsigned short ushort4v;
typedef __attribute__((ext_vector_type(3))) unsigned int uint3v;

#define AS1 __attribute__((address_space(1)))
#define AS3 __attribute__((address_space(3)))

__device__ inline unsigned short f2bf_rne(float x) {
    unsigned int u = __builtin_bit_cast(unsigned int, x);
    unsigned int r = (u + 0x7FFFu + ((u >> 16) & 1u)) >> 16;
    return (unsigned short)r;
}
__device__ inline float bf2f(unsigned short h) {
    return __builtin_bit_cast(float, (unsigned int)h << 16);
}

// ---------------- CSR build ----------------
__global__ void k_hist(const int* __restrict__ er, int* __restrict__ cnt, int E) {
    for (int e = blockIdx.x * blockDim.x + threadIdx.x; e < E; e += gridDim.x * blockDim.x)
        atomicAdd(&cnt[er[e]], 1);
}

__global__ void k_scan1(const int* __restrict__ cnt, int* __restrict__ ex,
                        int* __restrict__ bsum, int n) {
    __shared__ int s[256];
    int i = blockIdx.x * 256 + threadIdx.x;
    int v = (i < n) ? cnt[i] : 0;
    s[threadIdx.x] = v;
    __syncthreads();
    #pragma unroll
    for (int off = 1; off < 256; off <<= 1) {
        int t = (threadIdx.x >= (unsigned)off) ? s[threadIdx.x - off] : 0;
        __syncthreads();
        s[threadIdx.x] += t;
        __syncthreads();
    }
    if (i < n) ex[i] = s[threadIdx.x] - v;
    if (threadIdx.x == 255) bsum[blockIdx.x] = s[255];
}

__global__ void k_scan2(int* __restrict__ bsum, int nb) {
    __shared__ int s[512];
    int v = ((int)threadIdx.x < nb) ? bsum[threadIdx.x] : 0;
    s[threadIdx.x] = v;
    __syncthreads();
    #pragma unroll
    for (int off = 1; off < 512; off <<= 1) {
        int t = (threadIdx.x >= (unsigned)off) ? s[threadIdx.x - off] : 0;
        __syncthreads();
        s[threadIdx.x] += t;
        __syncthreads();
    }
    if ((int)threadIdx.x < nb) bsum[threadIdx.x] = s[threadIdx.x] - v;
}

__global__ void k_scan3(int* __restrict__ rp, int* __restrict__ ofs,
                        const int* __restrict__ bsum, const int* __restrict__ cnt,
                        int n) {
    int i = blockIdx.x * 256 + threadIdx.x;
    if (i < n) {
        int v = rp[i] + bsum[blockIdx.x];
        rp[i] = v;
        ofs[i] = v;
        if (i == n - 1) rp[n] = v + cnt[i];
    }
}

__global__ void k_scatter(const int* __restrict__ er, const int* __restrict__ ec,
                          const float* __restrict__ ev, int* __restrict__ ofs,
                          int2* __restrict__ ev2, int E) {
    for (int e = blockIdx.x * blockDim.x + threadIdx.x; e < E; e += gridDim.x * blockDim.x) {
        int r = er[e];
        int p = atomicAdd(&ofs[r], 1);
        ev2[p] = make_int2(ec[e], __builtin_bit_cast(int, ev[e]));
    }
}

// ---------------- weight split: W[K][M] fp32 -> [M][K] bf16 hi/lo ----------------
__global__ void k_split_w(const float* __restrict__ W, unsigned short* __restrict__ hi,
                          unsigned short* __restrict__ lo, int K, int M) {
    int i = blockIdx.x * 256 + threadIdx.x;
    if (i >= K * M) return;
    int k = i / M, m = i - k * M;
    float x = W[i];
    unsigned short h = f2bf_rne(x);
    unsigned short l = f2bf_rne(x - bf2f(h));
    hi[(size_t)m * K + k] = h;
    lo[(size_t)m * K + k] = l;
}

// ---------------- pack fp32 -> 24-bit (round-half-up on dropped byte) ----------------
__global__ __launch_bounds__(256)
void k_pack24(const float* __restrict__ in, unsigned int* __restrict__ out, long ngroup) {
    __shared__ unsigned int sp[768];
    long g0 = (long)blockIdx.x * 256;
    long g = g0 + threadIdx.x;
    float4 v = make_float4(0.f, 0.f, 0.f, 0.f);
    if (g < ngroup) v = *(const float4*)&in[g * 4];
    unsigned int t0 = (__builtin_bit_cast(unsigned int, v.x) + 0x80u) >> 8;
    unsigned int t1 = (__builtin_bit_cast(unsigned int, v.y) + 0x80u) >> 8;
    unsigned int t2 = (__builtin_bit_cast(unsigned int, v.z) + 0x80u) >> 8;
    unsigned int t3 = (__builtin_bit_cast(unsigned int, v.w) + 0x80u) >> 8;
    sp[threadIdx.x * 3 + 0] = t0 | (t1 << 24);
    sp[threadIdx.x * 3 + 1] = (t1 >> 8) | (t2 << 16);
    sp[threadIdx.x * 3 + 2] = (t2 >> 16) | (t3 << 8);
    __syncthreads();
    long nvalid = ngroup - g0;
    int total = (int)(nvalid >= 256 ? 768 : nvalid * 3);
    for (int i = threadIdx.x; i < total; i += 256) out[g0 * 3 + i] = sp[i];
}

// ---------------- GEMM1: C[N,256] = X[N,512] @ W1. fp32 A staged, split in-reg.
// 256 thr = 4 waves, block tile 64 x 256 (full M -> X read once).
__global__ __launch_bounds__(256, 4)
void k_gemm1w(const float* __restrict__ X, const unsigned short* __restrict__ Bh,
              const unsigned short* __restrict__ Bl, float* __restrict__ C, const int N) {
    constexpr int K = 512, M = 256, NT = K / 32;
    __shared__ char smem[16384];            // dbuf A: 2 x 64x32 fp32 = 16 KB; epilogue scratch aliases
    float* sX = (float*)smem;
    const int tid = threadIdx.x;
    const int lane = tid & 63;
    const int w = tid >> 6;                 // wave: col group AND staging row group
    const int lm = lane & 15, lk = lane >> 4;
    const int row0 = blockIdx.x * 64;
    const int col0 = w * 64;

    // staging: wave w stages rows [w*16, w*16+16), 2 loads of 8 rows; global kseg pre-swizzled
    const int kseg = (lane & 7) ^ ((lane >> 3) & 7);
    const int r0 = min(row0 + w * 16 + (lane >> 3), N - 1);
    const int r1 = min(row0 + w * 16 + 8 + (lane >> 3), N - 1);
    const size_t ga0 = (size_t)r0 * K + kseg * 4;
    const size_t ga1 = (size_t)r1 * K + kseg * 4;

    const unsigned short* bph = Bh + (size_t)(col0 + lm) * K + lk * 8;
    const unsigned short* bpl = Bl + (size_t)(col0 + lm) * K + lk * 8;

    f32x4 acc[4][4];
    #pragma unroll
    for (int i = 0; i < 4; ++i)
        #pragma unroll
        for (int j = 0; j < 4; ++j) acc[i][j] = (f32x4){0.f, 0.f, 0.f, 0.f};

    auto stage = [&](int b, int kk) {
        __builtin_amdgcn_global_load_lds((const AS1 void*)(X + ga0 + kk),
                                         (AS3 void*)(sX + b * 2048 + w * 512), 16, 0, 0);
        __builtin_amdgcn_global_load_lds((const AS1 void*)(X + ga1 + kk),
                                         (AS3 void*)(sX + b * 2048 + w * 512 + 256), 16, 0, 0);
    };

    stage(0, 0);
    __syncthreads();

    const int u0 = ((2 * lk) ^ (lm & 7)) * 4;       // float offsets of the 2 swizzled 16B units
    const int u1 = ((2 * lk + 1) ^ (lm & 7)) * 4;

    for (int t = 0; t < NT; ++t) {
        if (t + 1 < NT) stage((t + 1) & 1, (t + 1) * 32);
        const float* sb = sX + (t & 1) * 2048;
        const int kk = t * 32;
        short8 bhf[4], blf[4];
        #pragma unroll
        for (int nf = 0; nf < 4; ++nf) {
            const size_t o = (size_t)nf * 16 * K + kk;
            bhf[nf] = *(const short8*)(bph + o);
            blf[nf] = *(const short8*)(bpl + o);
        }
        #pragma unroll
        for (int mf = 0; mf < 4; ++mf) {
            const float* ab = sb + (mf * 16 + lm) * 32;
            f32x4 p0 = *(const f32x4*)(ab + u0);
            f32x4 p1 = *(const f32x4*)(ab + u1);
            float vv[8] = {p0.x, p0.y, p0.z, p0.w, p1.x, p1.y, p1.z, p1.w};
            short8 ah, al;
            #pragma unroll
            for (int j = 0; j < 8; ++j) {
                unsigned int u = __builtin_bit_cast(unsigned int, vv[j]);
                ah[j] = (short)(u >> 16);                                   // truncated hi
                float hi = __builtin_bit_cast(float, u & 0xFFFF0000u);
                al[j] = (short)f2bf_rne(vv[j] - hi);                        // exact remainder -> bf16
            }
            #pragma unroll
            for (int nf = 0; nf < 4; ++nf) {
                acc[mf][nf] = __builtin_amdgcn_mfma_f32_16x16x32_bf16(ah, bhf[nf], acc[mf][nf], 0, 0, 0);
                acc[mf][nf] = __builtin_amdgcn_mfma_f32_16x16x32_bf16(ah, blf[nf], acc[mf][nf], 0, 0, 0);
                acc[mf][nf] = __builtin_amdgcn_mfma_f32_16x16x32_bf16(al, bhf[nf], acc[mf][nf], 0, 0, 0);
            }
        }
        __syncthreads();
    }

    // epilogue: LDS bounce per mf-slice -> float4 coalesced stores (full 128B lines)
    float* sc = (float*)smem;               // 16 rows x 256 cols fp32 = 16 KB
    #pragma unroll
    for (int mf = 0; mf < 4; ++mf) {
        __syncthreads();
        #pragma unroll
        for (int nf = 0; nf < 4; ++nf)
            #pragma unroll
            for (int r = 0; r < 4; ++r) {
                const int rl = lk * 4 + r;
                const int col = col0 + nf * 16 + lm;
                sc[rl * M + (col ^ (lk << 3))] = acc[mf][nf][r];
            }
        __syncthreads();
        #pragma unroll
        for (int i = 0; i < 4; ++i) {
            const int idx = i * 256 + tid;
            const int rl = idx >> 6, u = idx & 63;
            const int grow = row0 + mf * 16 + rl;
            if (grow < N) {
                f32x4 v = *(const f32x4*)&sc[rl * M + ((u * 4) ^ (((rl >> 2) & 3) << 3))];
                *(f32x4*)&C[(size_t)grow * M + u * 4] = v;
            }
        }
    }
}

// ---------------- GEMM (A pre-split bf16 h/l): block tile 64 x (64*NFW), full M ----------------
template <int K, int NFW>
__global__ __launch_bounds__(256, 4)
void k_gemm_bt(const unsigned short* __restrict__ Ah, const unsigned short* __restrict__ Al,
               const unsigned short* __restrict__ Bh, const unsigned short* __restrict__ Bl,
               float* __restrict__ C, const int N) {
    constexpr int M = 64 * NFW;
    constexpr int NT = K / 32;
    constexpr int UPR = 16 * NFW;           // float4 units per row
    __shared__ char smem[16384];
    unsigned short* sAh = (unsigned short*)smem;          // [2][64*32]
    unsigned short* sAl = sAh + 4096;
    const int tid = threadIdx.x;
    const int lane = tid & 63;
    const int w = tid >> 6;
    const int lm = lane & 15, lk = lane >> 4;
    const int row0 = blockIdx.x * 64;
    const int col0 = w * (16 * NFW);

    const int kseg = (lane & 3) ^ ((lane >> 2) & 3);
    const int gr = min(row0 + w * 16 + (lane >> 2), N - 1);
    const size_t ga = (size_t)gr * K + kseg * 8;

    const int aoff = lm * 32 + ((lk ^ (lm & 3)) * 8);

    const unsigned short* bph = Bh + (size_t)(col0 + lm) * K + lk * 8;
    const unsigned short* bpl = Bl + (size_t)(col0 + lm) * K + lk * 8;

    f32x4 acc[4][NFW];
    #pragma unroll
    for (int i = 0; i < 4; ++i)
        #pragma unroll
        for (int j = 0; j < NFW; ++j) acc[i][j] = (f32x4){0.f, 0.f, 0.f, 0.f};

    auto stage = [&](int b, int kk) {
        __builtin_amdgcn_global_load_lds((const AS1 void*)(Ah + ga + kk),
                                         (AS3 void*)(sAh + b * 2048 + w * 512), 16, 0, 0);
        __builtin_amdgcn_global_load_lds((const AS1 void*)(Al + ga + kk),
                                         (AS3 void*)(sAl + b * 2048 + w * 512), 16, 0, 0);
    };

    stage(0, 0);
    __syncthreads();

    for (int t = 0; t < NT; ++t) {
        if (t + 1 < NT) stage((t + 1) & 1, (t + 1) * 32);
        const int b = t & 1;
        const int kk = t * 32;
        short8 bhf[NFW], blf[NFW];
        #pragma unroll
        for (int nf = 0; nf < NFW; ++nf) {
            const size_t o = (size_t)nf * 16 * K + kk;
            bhf[nf] = *(const short8*)(bph + o);
            blf[nf] = *(const short8*)(bpl + o);
        }
        #pragma unroll
        for (int mf = 0; mf < 4; ++mf) {
            short8 ah = *(const short8*)&sAh[b * 2048 + aoff + mf * 512];
            short8 al = *(const short8*)&sAl[b * 2048 + aoff + mf * 512];
            #pragma unroll
            for (int nf = 0; nf < NFW; ++nf) {
                acc[mf][nf] = __builtin_amdgcn_mfma_f32_16x16x32_bf16(ah, bhf[nf], acc[mf][nf], 0, 0, 0);
                acc[mf][nf] = __builtin_amdgcn_mfma_f32_16x16x32_bf16(ah, blf[nf], acc[mf][nf], 0, 0, 0);
                acc[mf][nf] = __builtin_amdgcn_mfma_f32_16x16x32_bf16(al, bhf[nf], acc[mf][nf], 0, 0, 0);
            }
        }
        __syncthreads();
    }

    float* sc = (float*)smem;               // 16 x M fp32 (<= 16 KB)
    #pragma unroll
    for (int mf = 0; mf < 4; ++mf) {
        __syncthreads();
        #pragma unroll
        for (int nf = 0; nf < NFW; ++nf)
            #pragma unroll
            for (int r = 0; r < 4; ++r) {
                const int rl = lk * 4 + r;
                const int col = col0 + nf * 16 + lm;
                sc[rl * M + (col ^ (lk << 3))] = acc[mf][nf][r];
            }
        __syncthreads();
        #pragma unroll
        for (int i = 0; i < (16 * UPR) / 256; ++i) {
            const int idx = i * 256 + tid;
            const int rl = idx / UPR, u = idx % UPR;
            const int grow = row0 + mf * 16 + rl;
            if (grow < N) {
                f32x4 v = *(const f32x4*)&sc[rl * M + ((u * 4) ^ (((rl >> 2) & 3) << 3))];
                *(f32x4*)&C[(size_t)grow * M + u * 4] = v;
            }
        }
    }
}

// ---------------- SpMM on 24-bit packed input, wave-per-row, fused bias+relu+split ----------------
__global__ __launch_bounds__(256)
void k_spmm256p(const int* __restrict__ rp, const int2* __restrict__ ev2,
                const unsigned int* __restrict__ in24, const float* __restrict__ bias,
                unsigned short* __restrict__ oh, unsigned short* __restrict__ ol, int N) {
    const int lane = threadIdx.x & 63;
    int r = __builtin_amdgcn_readfirstlane(blockIdx.x * 4 + (threadIdx.x >> 6));
    if (r >= N) return;
    const int e0 = __builtin_amdgcn_readfirstlane(rp[r]);
    const int e1 = __builtin_amdgcn_readfirstlane(rp[r + 1]);
    f32x4 acc = {0.f, 0.f, 0.f, 0.f};
    const unsigned int* base = in24 + lane * 3;

    #pragma unroll 4
    for (int e = e0; e < e1; ++e) {
        int2 p = ev2[e];
        const unsigned int* gp = base + (size_t)p.x * 192;
        unsigned int dx = gp[0], dy = gp[1], dz = gp[2];
        float val = __builtin_bit_cast(float, p.y);
        unsigned int q0 = dx & 0xFFFFFFu;
        unsigned int q1 = (dx >> 24) | ((dy & 0xFFFFu) << 8);
        unsigned int q2 = (dy >> 16) | ((dz & 0xFFu) << 16);
        unsigned int q3 = dz >> 8;
        acc[0] = fmaf(val, __builtin_bit_cast(float, q0 << 8), acc[0]);
        acc[1] = fmaf(val, __builtin_bit_cast(float, q1 << 8), acc[1]);
        acc[2] = fmaf(val, __builtin_bit_cast(float, q2 << 8), acc[2]);
        acc[3] = fmaf(val, __builtin_bit_cast(float, q3 << 8), acc[3]);
    }

    f32x4 bv = *(const f32x4*)&bias[lane * 4];
    ushort4v h, l;
    #pragma unroll
    for (int j = 0; j < 4; ++j) {
        float o = fmaxf(acc[j] + bv[j], 0.f);
        unsigned short hh = f2bf_rne(o);
        h[j] = hh;
        l[j] = f2bf_rne(o - bf2f(hh));
    }
    *(ushort4v*)&oh[(size_t)r * 256 + lane * 4] = h;
    *(ushort4v*)&ol[(size_t)r * 256 + lane * 4] = l;
}

// ---------------- SpMM F=128 (fp32 in) + fused bias/relu + final dense ----------------
__global__ __launch_bounds__(256)
void k_spmm128d(const int* __restrict__ rp, const int2* __restrict__ ev2,
                const float* __restrict__ in, const float* __restrict__ b3,
                const float* __restrict__ Wd, const float* __restrict__ bd,
                float* __restrict__ out, int N) {
    __shared__ float Ws[H4 * NCLASS];
    __shared__ float hrow[4][H4];
    {
        int i = threadIdx.x * 8;
        *(f32x4*)&Ws[i] = *(const f32x4*)&Wd[i];
        *(f32x4*)&Ws[i + 4] = *(const f32x4*)&Wd[i + 4];
    }
    __syncthreads();

    const int lane = threadIdx.x & 63;
    const int w = threadIdx.x >> 6;
    int r = __builtin_amdgcn_readfirstlane(blockIdx.x * 4 + w);
    if (r >= N) return;
    const int e0 = __builtin_amdgcn_readfirstlane(rp[r]);
    const int e1 = __builtin_amdgcn_readfirstlane(rp[r + 1]);
    float a0 = 0.f, a1 = 0.f;
    const float* base = in + (size_t)lane * 2;

    #pragma unroll 4
    for (int e = e0; e < e1; ++e) {
        int2 p = ev2[e];
        float2 x = *(const float2*)(base + (size_t)p.x * 128);
        float v = __builtin_bit_cast(float, p.y);
        a0 = fmaf(v, x.x, a0);
        a1 = fmaf(v, x.y, a1);
    }

    float2 hb;
    hb.x = fmaxf(a0 + b3[lane * 2 + 0], 0.f);
    hb.y = fmaxf(a1 + b3[lane * 2 + 1], 0.f);
    *(float2*)&hrow[w][lane * 2] = hb;

    const int c = lane & 15, q = lane >> 4;
    float s = 0.f;
    #pragma unroll
    for (int k = q * 32; k < q * 32 + 32; ++k)
        s = fmaf(hrow[w][k], Ws[k * NCLASS + c], s);
    s += __shfl_xor(s, 16);
    s += __shfl_xor(s, 32);
    if (lane < 16) out[(size_t)r * NCLASS + lane] = s + bd[lane];
}

extern "C" void kernel_launch(void* const* d_in, const int* in_sizes, int n_in,
                              void* d_out, int out_size, void* d_ws, size_t ws_size,
                              hipStream_t stream) {
    const float* x  = (const float*)d_in[0];
    const int*   er = (const int*)d_in[1];
    const int*   ec = (const int*)d_in[2];
    const float* ev = (const float*)d_in[3];
    const float* W1 = (const float*)d_in[4];
    const float* b1 = (const float*)d_in[5];
    const float* W2 = (const float*)d_in[6];
    const float* b2 = (const float*)d_in[7];
    const float* W3 = (const float*)d_in[8];
    const float* b3 = (const float*)d_in[9];
    const float* Wd = (const float*)d_in[10];
    const float* bd = (const float*)d_in[11];
    float* out = (float*)d_out;

    const int N = in_sizes[0] / NFEAT;
    const int E = in_sizes[1];

    char* w = (char*)d_ws;
    auto alloc = [&](size_t bytes) { char* p = w; w += (bytes + 255) & ~(size_t)255; return p; };
    float* C   = (float*)alloc((size_t)N * 256 * 4);
    unsigned int* C24 = (unsigned int*)alloc((size_t)N * 256 * 3);
    unsigned short* hh = (unsigned short*)alloc((size_t)N * 256 * 2);
    unsigned short* hl = (unsigned short*)alloc((size_t)N * 256 * 2);
    int* cnt  = (int*)alloc((size_t)N * 4);
    int* rp   = (int*)alloc((size_t)(N + 1) * 4);
    int* ofs  = (int*)alloc((size_t)N * 4);
    int2* ev2 = (int2*)alloc((size_t)E * 8);
    int* bsum = (int*)alloc(4096);
    unsigned short* W1h = (unsigned short*)alloc((size_t)NFEAT * H2 * 2);
    unsigned short* W1l = (unsigned short*)alloc((size_t)NFEAT * H2 * 2);
    unsigned short* W2h = (unsigned short*)alloc((size_t)H2 * H3 * 2);
    unsigned short* W2l = (unsigned short*)alloc((size_t)H2 * H3 * 2);
    unsigned short* W3h = (unsigned short*)alloc((size_t)H3 * H4 * 2);
    unsigned short* W3l = (unsigned short*)alloc((size_t)H3 * H4 * 2);

    const int nb = (N + 255) / 256;

    hipMemsetAsync(cnt, 0, (size_t)N * 4, stream);
    k_hist<<<1024, 256, 0, stream>>>(er, cnt, E);
    k_scan1<<<nb, 256, 0, stream>>>(cnt, rp, bsum, N);
    k_scan2<<<1, 512, 0, stream>>>(bsum, nb);
    k_scan3<<<nb, 256, 0, stream>>>(rp, ofs, bsum, cnt, N);
    k_scatter<<<1024, 256, 0, stream>>>(er, ec, ev, ofs, ev2, E);

    k_split_w<<<(NFEAT * H2 + 255) / 256, 256, 0, stream>>>(W1, W1h, W1l, NFEAT, H2);
    k_split_w<<<(H2 * H3 + 255) / 256, 256, 0, stream>>>(W2, W2h, W2l, H2, H3);
    k_split_w<<<(H3 * H4 + 255) / 256, 256, 0, stream>>>(W3, W3h, W3l, H3, H4);

    const int rgrid = (N + 63) / 64;
    const int sgrid = (N + 3) / 4;
    const long ngroup = (long)N * 256 / 4;
    const int pgrid = (int)((ngroup + 255) / 256);

    k_gemm1w<<<rgrid, 256, 0, stream>>>(x, W1h, W1l, C, N);
    k_pack24<<<pgrid, 256, 0, stream>>>(C, C24, ngroup);
    k_spmm256p<<<sgrid, 256, 0, stream>>>(rp, ev2, C24, b1, hh, hl, N);

    k_gemm_bt<H2, 4><<<rgrid, 256, 0, stream>>>(hh, hl, W2h, W2l, C, N);
    k_pack24<<<pgrid, 256, 0, stream>>>(C, C24, ngroup);
    k_spmm256p<<<sgrid, 256, 0, stream>>>(rp, ev2, C24, b2, hh, hl, N);

    k_gemm_bt<H3, 2><<<rgrid, 256, 0, stream>>>(hh, hl, W3h, W3l, C, N);
    k_spmm128d<<<sgrid, 256, 0, stream>>>(rp, ev2, C, b3, Wd, bd, out, N);
}

// Round 10
// 1005.855 us; speedup vs baseline: 1.0216x; 1.0216x over previous
//
#include <hip/hip_runtime.h>
#include <hip/hip_bf16.h>
#include <cstdint>
#include <cstddef>

#define NFEAT 512
#define H2 256
#define H3 256
#define H4 128
#define NCLASS 16

typedef __attribute__((ext_vector_type(8))) short short8;
typedef __attribute__((ext_vector_type(4))) float f32x4;
typedef __attribute__((ext_vector_type(4))) unsigned short ushort4v;

#define AS1 __attribute__((address_space(1)))
#define AS3 __attribute__((address_space(3)))

__device__ inline unsigned short f2bf_rne(float x) {
    unsigned int u = __builtin_bit_cast(unsigned int, x);
    unsigned int r = (u + 0x7FFFu + ((u >> 16) & 1u)) >> 16;
    return (unsigned short)r;
}
__device__ inline float bf2f(unsigned short h) {
    return __builtin_bit_cast(float, (unsigned int)h << 16);
}

// ---------------- CSR build ----------------
__global__ void k_hist(const int* __restrict__ er, int* __restrict__ cnt, int E) {
    for (int e = blockIdx.x * blockDim.x + threadIdx.x; e < E; e += gridDim.x * blockDim.x)
        atomicAdd(&cnt[er[e]], 1);
}

__global__ void k_scan1(const int* __restrict__ cnt, int* __restrict__ ex,
                        int* __restrict__ bsum, int n) {
    __shared__ int s[256];
    int i = blockIdx.x * 256 + threadIdx.x;
    int v = (i < n) ? cnt[i] : 0;
    s[threadIdx.x] = v;
    __syncthreads();
    #pragma unroll
    for (int off = 1; off < 256; off <<= 1) {
        int t = (threadIdx.x >= (unsigned)off) ? s[threadIdx.x - off] : 0;
        __syncthreads();
        s[threadIdx.x] += t;
        __syncthreads();
    }
    if (i < n) ex[i] = s[threadIdx.x] - v;
    if (threadIdx.x == 255) bsum[blockIdx.x] = s[255];
}

__global__ void k_scan2(int* __restrict__ bsum, int nb) {
    __shared__ int s[512];
    int v = ((int)threadIdx.x < nb) ? bsum[threadIdx.x] : 0;
    s[threadIdx.x] = v;
    __syncthreads();
    #pragma unroll
    for (int off = 1; off < 512; off <<= 1) {
        int t = (threadIdx.x >= (unsigned)off) ? s[threadIdx.x - off] : 0;
        __syncthreads();
        s[threadIdx.x] += t;
        __syncthreads();
    }
    if ((int)threadIdx.x < nb) bsum[threadIdx.x] = s[threadIdx.x] - v;
}

__global__ void k_scan3(int* __restrict__ rp, int* __restrict__ ofs,
                        const int* __restrict__ bsum, const int* __restrict__ cnt,
                        int n) {
    int i = blockIdx.x * 256 + threadIdx.x;
    if (i < n) {
        int v = rp[i] + bsum[blockIdx.x];
        rp[i] = v;
        ofs[i] = v;
        if (i == n - 1) rp[n] = v + cnt[i];
    }
}

__global__ void k_scatter(const int* __restrict__ er, const int* __restrict__ ec,
                          const float* __restrict__ ev, int* __restrict__ ofs,
                          int2* __restrict__ ev2, int E) {
    for (int e = blockIdx.x * blockDim.x + threadIdx.x; e < E; e += gridDim.x * blockDim.x) {
        int r = er[e];
        int p = atomicAdd(&ofs[r], 1);
        ev2[p] = make_int2(ec[e], __builtin_bit_cast(int, ev[e]));
    }
}

// ---------------- weight split: W[K][M] fp32 -> [M][K] bf16 hi/lo ----------------
__global__ void k_split_w(const float* __restrict__ W, unsigned short* __restrict__ hi,
                          unsigned short* __restrict__ lo, int K, int M) {
    int i = blockIdx.x * 256 + threadIdx.x;
    if (i >= K * M) return;
    int k = i / M, m = i - k * M;
    float x = W[i];
    unsigned short h = f2bf_rne(x);
    unsigned short l = f2bf_rne(x - bf2f(h));
    hi[(size_t)m * K + k] = h;
    lo[(size_t)m * K + k] = l;
}

// ---------------- pack fp32 -> 24-bit (round-half-up on dropped byte) ----------------
__global__ __launch_bounds__(256)
void k_pack24(const float* __restrict__ in, unsigned int* __restrict__ out, long ngroup) {
    __shared__ unsigned int sp[768];
    long g0 = (long)blockIdx.x * 256;
    long g = g0 + threadIdx.x;
    float4 v = make_float4(0.f, 0.f, 0.f, 0.f);
    if (g < ngroup) v = *(const float4*)&in[g * 4];
    unsigned int t0 = (__builtin_bit_cast(unsigned int, v.x) + 0x80u) >> 8;
    unsigned int t1 = (__builtin_bit_cast(unsigned int, v.y) + 0x80u) >> 8;
    unsigned int t2 = (__builtin_bit_cast(unsigned int, v.z) + 0x80u) >> 8;
    unsigned int t3 = (__builtin_bit_cast(unsigned int, v.w) + 0x80u) >> 8;
    sp[threadIdx.x * 3 + 0] = t0 | (t1 << 24);
    sp[threadIdx.x * 3 + 1] = (t1 >> 8) | (t2 << 16);
    sp[threadIdx.x * 3 + 2] = (t2 >> 16) | (t3 << 8);
    __syncthreads();
    long nvalid = ngroup - g0;
    int total = (int)(nvalid >= 256 ? 768 : nvalid * 3);
    for (int i = threadIdx.x; i < total; i += 256) out[g0 * 3 + i] = sp[i];
}

// ---------------- GEMM1: C[N,256] = X[N,512] @ W1. fp32 staged -> cooperative LDS
// convert to bf16 hi/lo (each element converted ONCE per block) -> gemm_bt main loop.
// 256 thr = 4 waves, block tile 64 x 256 (full M -> X read once). 2-deep pipeline.
__global__ __launch_bounds__(256, 4)
void k_gemm1x(const float* __restrict__ X, const unsigned short* __restrict__ Bh,
              const unsigned short* __restrict__ Bl, float* __restrict__ C, const int N) {
    constexpr int K = 512, M = 256, NT = K / 32;
    __shared__ char smem[32768];
    float* sXf = (float*)smem;                               // 2 x 64x32 fp32 (16 KB)
    unsigned short* sAh = (unsigned short*)(smem + 16384);   // 2 x 64x32 bf16 (8 KB)
    unsigned short* sAl = (unsigned short*)(smem + 24576);   // 2 x 64x32 bf16 (8 KB)
    const int tid = threadIdx.x;
    const int lane = tid & 63;
    const int w = tid >> 6;
    const int lm = lane & 15, lk = lane >> 4;
    const int row0 = blockIdx.x * 64;
    const int col0 = w * 64;

    // fp32 staging: wave w stages its rows [w*16, w*16+16); 16B k-unit pre-swizzled by row&7
    const int kseg = (lane & 7) ^ ((lane >> 3) & 7);
    const int r0 = min(row0 + w * 16 + (lane >> 3), N - 1);
    const int r1 = min(row0 + w * 16 + 8 + (lane >> 3), N - 1);
    const size_t ga0 = (size_t)r0 * K + kseg * 4;
    const size_t ga1 = (size_t)r1 * K + kseg * 4;

    // convert mapping: wave w converts its OWN staged rows; thread -> (row, k-octet)
    const int crow = w * 16 + (lane >> 2);       // local row 0..63
    const int ch = lane & 3;                     // which 8-k chunk
    const int cu0 = ((2 * ch) ^ (crow & 7)) * 4; // fp32 unit offsets (floats)
    const int cu1 = ((2 * ch + 1) ^ (crow & 7)) * 4;
    const int cwo = crow * 32 + (ch ^ (crow & 3)) * 8;  // bf16 write offset (shorts)

    const unsigned short* bph = Bh + (size_t)(col0 + lm) * K + lk * 8;
    const unsigned short* bpl = Bl + (size_t)(col0 + lm) * K + lk * 8;
    const int aoff = lm * 32 + ((lk ^ (lm & 3)) * 8);   // + mf*512

    f32x4 acc[4][4];
    #pragma unroll
    for (int i = 0; i < 4; ++i)
        #pragma unroll
        for (int j = 0; j < 4; ++j) acc[i][j] = (f32x4){0.f, 0.f, 0.f, 0.f};

    auto stage = [&](int b, int kk) {
        __builtin_amdgcn_global_load_lds((const AS1 void*)(X + ga0 + kk),
                                         (AS3 void*)(sXf + b * 2048 + w * 512), 16, 0, 0);
        __builtin_amdgcn_global_load_lds((const AS1 void*)(X + ga1 + kk),
                                         (AS3 void*)(sXf + b * 2048 + w * 512 + 256), 16, 0, 0);
    };

    auto convert = [&](int b) {
        const float* src = sXf + b * 2048 + crow * 32;
        f32x4 p0 = *(const f32x4*)(src + cu0);
        f32x4 p1 = *(const f32x4*)(src + cu1);
        float vv[8] = {p0.x, p0.y, p0.z, p0.w, p1.x, p1.y, p1.z, p1.w};
        short8 ah, al;
        #pragma unroll
        for (int j = 0; j < 8; ++j) {
            unsigned int u = __builtin_bit_cast(unsigned int, vv[j]);
            ah[j] = (short)(u >> 16);                           // truncated hi
            float hi = __builtin_bit_cast(float, u & 0xFFFF0000u);
            al[j] = (short)f2bf_rne(vv[j] - hi);                // exact remainder -> bf16
        }
        *(short8*)&sAh[b * 2048 + cwo] = ah;
        *(short8*)&sAl[b * 2048 + cwo] = al;
    };

    // prologue: fill sXf[0], convert it, prefetch sXf[1]
    stage(0, 0);
    __syncthreads();                 // drain stage(0)
    convert(0);
    stage(1, 32);
    __syncthreads();                 // sAh[0] visible; stage(1) drained

    for (int t = 0; t < NT; ++t) {
        const int b = t & 1;
        if (t + 2 < NT) stage(b, (t + 2) * 32);      // sXf[b] free: convert(t) done last iter
        const int kk = t * 32;
        short8 bhf[4], blf[4];
        #pragma unroll
        for (int nf = 0; nf < 4; ++nf) {
            const size_t o = (size_t)nf * 16 * K + kk;
            bhf[nf] = *(const short8*)(bph + o);
            blf[nf] = *(const short8*)(bpl + o);
        }
        #pragma unroll
        for (int mf = 0; mf < 4; ++mf) {
            short8 ah = *(const short8*)&sAh[b * 2048 + aoff + mf * 512];
            short8 al = *(const short8*)&sAl[b * 2048 + aoff + mf * 512];
            #pragma unroll
            for (int nf = 0; nf < 4; ++nf) {
                acc[mf][nf] = __builtin_amdgcn_mfma_f32_16x16x32_bf16(ah, bhf[nf], acc[mf][nf], 0, 0, 0);
                acc[mf][nf] = __builtin_amdgcn_mfma_f32_16x16x32_bf16(ah, blf[nf], acc[mf][nf], 0, 0, 0);
                acc[mf][nf] = __builtin_amdgcn_mfma_f32_16x16x32_bf16(al, bhf[nf], acc[mf][nf], 0, 0, 0);
            }
        }
        if (t + 1 < NT) convert(b ^ 1);              // sXf[b^1] staged iter t-1, drained at last barrier
        __syncthreads();                             // drains stage(t+2); publishes convert(t+1)
    }

    // epilogue: LDS bounce per mf-slice -> float4 coalesced stores (aliases sXf region)
    float* sc = (float*)smem;               // 16 rows x 256 cols fp32 = 16 KB
    #pragma unroll
    for (int mf = 0; mf < 4; ++mf) {
        __syncthreads();
        #pragma unroll
        for (int nf = 0; nf < 4; ++nf)
            #pragma unroll
            for (int r = 0; r < 4; ++r) {
                const int rl = lk * 4 + r;
                const int col = col0 + nf * 16 + lm;
                sc[rl * M + (col ^ (lk << 3))] = acc[mf][nf][r];
            }
        __syncthreads();
        #pragma unroll
        for (int i = 0; i < 4; ++i) {
            const int idx = i * 256 + tid;
            const int rl = idx >> 6, u = idx & 63;
            const int grow = row0 + mf * 16 + rl;
            if (grow < N) {
                f32x4 v = *(const f32x4*)&sc[rl * M + ((u * 4) ^ (((rl >> 2) & 3) << 3))];
                *(f32x4*)&C[(size_t)grow * M + u * 4] = v;
            }
        }
    }
}

// ---------------- GEMM (A pre-split bf16 h/l): block tile 64 x (64*NFW), full M ----------------
template <int K, int NFW>
__global__ __launch_bounds__(256, 4)
void k_gemm_bt(const unsigned short* __restrict__ Ah, const unsigned short* __restrict__ Al,
               const unsigned short* __restrict__ Bh, const unsigned short* __restrict__ Bl,
               float* __restrict__ C, const int N) {
    constexpr int M = 64 * NFW;
    constexpr int NT = K / 32;
    constexpr int UPR = 16 * NFW;           // float4 units per row
    __shared__ char smem[16384];
    unsigned short* sAh = (unsigned short*)smem;          // [2][64*32]
    unsigned short* sAl = sAh + 4096;
    const int tid = threadIdx.x;
    const int lane = tid & 63;
    const int w = tid >> 6;
    const int lm = lane & 15, lk = lane >> 4;
    const int row0 = blockIdx.x * 64;
    const int col0 = w * (16 * NFW);

    const int kseg = (lane & 3) ^ ((lane >> 2) & 3);
    const int gr = min(row0 + w * 16 + (lane >> 2), N - 1);
    const size_t ga = (size_t)gr * K + kseg * 8;

    const int aoff = lm * 32 + ((lk ^ (lm & 3)) * 8);

    const unsigned short* bph = Bh + (size_t)(col0 + lm) * K + lk * 8;
    const unsigned short* bpl = Bl + (size_t)(col0 + lm) * K + lk * 8;

    f32x4 acc[4][NFW];
    #pragma unroll
    for (int i = 0; i < 4; ++i)
        #pragma unroll
        for (int j = 0; j < NFW; ++j) acc[i][j] = (f32x4){0.f, 0.f, 0.f, 0.f};

    auto stage = [&](int b, int kk) {
        __builtin_amdgcn_global_load_lds((const AS1 void*)(Ah + ga + kk),
                                         (AS3 void*)(sAh + b * 2048 + w * 512), 16, 0, 0);
        __builtin_amdgcn_global_load_lds((const AS1 void*)(Al + ga + kk),
                                         (AS3 void*)(sAl + b * 2048 + w * 512), 16, 0, 0);
    };

    stage(0, 0);
    __syncthreads();

    for (int t = 0; t < NT; ++t) {
        if (t + 1 < NT) stage((t + 1) & 1, (t + 1) * 32);
        const int b = t & 1;
        const int kk = t * 32;
        short8 bhf[NFW], blf[NFW];
        #pragma unroll
        for (int nf = 0; nf < NFW; ++nf) {
            const size_t o = (size_t)nf * 16 * K + kk;
            bhf[nf] = *(const short8*)(bph + o);
            blf[nf] = *(const short8*)(bpl + o);
        }
        #pragma unroll
        for (int mf = 0; mf < 4; ++mf) {
            short8 ah = *(const short8*)&sAh[b * 2048 + aoff + mf * 512];
            short8 al = *(const short8*)&sAl[b * 2048 + aoff + mf * 512];
            #pragma unroll
            for (int nf = 0; nf < NFW; ++nf) {
                acc[mf][nf] = __builtin_amdgcn_mfma_f32_16x16x32_bf16(ah, bhf[nf], acc[mf][nf], 0, 0, 0);
                acc[mf][nf] = __builtin_amdgcn_mfma_f32_16x16x32_bf16(ah, blf[nf], acc[mf][nf], 0, 0, 0);
                acc[mf][nf] = __builtin_amdgcn_mfma_f32_16x16x32_bf16(al, bhf[nf], acc[mf][nf], 0, 0, 0);
            }
        }
        __syncthreads();
    }

    float* sc = (float*)smem;               // 16 x M fp32 (<= 16 KB)
    #pragma unroll
    for (int mf = 0; mf < 4; ++mf) {
        __syncthreads();
        #pragma unroll
        for (int nf = 0; nf < NFW; ++nf)
            #pragma unroll
            for (int r = 0; r < 4; ++r) {
                const int rl = lk * 4 + r;
                const int col = col0 + nf * 16 + lm;
                sc[rl * M + (col ^ (lk << 3))] = acc[mf][nf][r];
            }
        __syncthreads();
        #pragma unroll
        for (int i = 0; i < (16 * UPR) / 256; ++i) {
            const int idx = i * 256 + tid;
            const int rl = idx / UPR, u = idx % UPR;
            const int grow = row0 + mf * 16 + rl;
            if (grow < N) {
                f32x4 v = *(const f32x4*)&sc[rl * M + ((u * 4) ^ (((rl >> 2) & 3) << 3))];
                *(f32x4*)&C[(size_t)grow * M + u * 4] = v;
            }
        }
    }
}

// ---------------- SpMM on 24-bit packed input, wave-per-row, fused bias+relu+split ----------------
__global__ __launch_bounds__(256)
void k_spmm256p(const int* __restrict__ rp, const int2* __restrict__ ev2,
                const unsigned int* __restrict__ in24, const float* __restrict__ bias,
                unsigned short* __restrict__ oh, unsigned short* __restrict__ ol, int N) {
    const int lane = threadIdx.x & 63;
    int r = __builtin_amdgcn_readfirstlane(blockIdx.x * 4 + (threadIdx.x >> 6));
    if (r >= N) return;
    const int e0 = __builtin_amdgcn_readfirstlane(rp[r]);
    const int e1 = __builtin_amdgcn_readfirstlane(rp[r + 1]);
    f32x4 acc = {0.f, 0.f, 0.f, 0.f};
    const unsigned int* base = in24 + lane * 3;

    #pragma unroll 4
    for (int e = e0; e < e1; ++e) {
        int2 p = ev2[e];
        const unsigned int* gp = base + (size_t)p.x * 192;
        unsigned int dx = gp[0], dy = gp[1], dz = gp[2];
        float val = __builtin_bit_cast(float, p.y);
        unsigned int q0 = dx & 0xFFFFFFu;
        unsigned int q1 = (dx >> 24) | ((dy & 0xFFFFu) << 8);
        unsigned int q2 = (dy >> 16) | ((dz & 0xFFu) << 16);
        unsigned int q3 = dz >> 8;
        acc[0] = fmaf(val, __builtin_bit_cast(float, q0 << 8), acc[0]);
        acc[1] = fmaf(val, __builtin_bit_cast(float, q1 << 8), acc[1]);
        acc[2] = fmaf(val, __builtin_bit_cast(float, q2 << 8), acc[2]);
        acc[3] = fmaf(val, __builtin_bit_cast(float, q3 << 8), acc[3]);
    }

    f32x4 bv = *(const f32x4*)&bias[lane * 4];
    ushort4v h, l;
    #pragma unroll
    for (int j = 0; j < 4; ++j) {
        float o = fmaxf(acc[j] + bv[j], 0.f);
        unsigned short hh = f2bf_rne(o);
        h[j] = hh;
        l[j] = f2bf_rne(o - bf2f(hh));
    }
    *(ushort4v*)&oh[(size_t)r * 256 + lane * 4] = h;
    *(ushort4v*)&ol[(size_t)r * 256 + lane * 4] = l;
}

// ---------------- SpMM F=128 (fp32 in) + fused bias/relu + final dense ----------------
__global__ __launch_bounds__(256)
void k_spmm128d(const int* __restrict__ rp, const int2* __restrict__ ev2,
                const float* __restrict__ in, const float* __restrict__ b3,
                const float* __restrict__ Wd, const float* __restrict__ bd,
                float* __restrict__ out, int N) {
    __shared__ float Ws[H4 * NCLASS];
    __shared__ float hrow[4][H4];
    {
        int i = threadIdx.x * 8;
        *(f32x4*)&Ws[i] = *(const f32x4*)&Wd[i];
        *(f32x4*)&Ws[i + 4] = *(const f32x4*)&Wd[i + 4];
    }
    __syncthreads();

    const int lane = threadIdx.x & 63;
    const int w = threadIdx.x >> 6;
    int r = __builtin_amdgcn_readfirstlane(blockIdx.x * 4 + w);
    if (r >= N) return;
    const int e0 = __builtin_amdgcn_readfirstlane(rp[r]);
    const int e1 = __builtin_amdgcn_readfirstlane(rp[r + 1]);
    float a0 = 0.f, a1 = 0.f;
    const float* base = in + (size_t)lane * 2;

    #pragma unroll 4
    for (int e = e0; e < e1; ++e) {
        int2 p = ev2[e];
        float2 x = *(const float2*)(base + (size_t)p.x * 128);
        float v = __builtin_bit_cast(float, p.y);
        a0 = fmaf(v, x.x, a0);
        a1 = fmaf(v, x.y, a1);
    }

    float2 hb;
    hb.x = fmaxf(a0 + b3[lane * 2 + 0], 0.f);
    hb.y = fmaxf(a1 + b3[lane * 2 + 1], 0.f);
    *(float2*)&hrow[w][lane * 2] = hb;

    const int c = lane & 15, q = lane >> 4;
    float s = 0.f;
    #pragma unroll
    for (int k = q * 32; k < q * 32 + 32; ++k)
        s = fmaf(hrow[w][k], Ws[k * NCLASS + c], s);
    s += __shfl_xor(s, 16);
    s += __shfl_xor(s, 32);
    if (lane < 16) out[(size_t)r * NCLASS + lane] = s + bd[lane];
}

extern "C" void kernel_launch(void* const* d_in, const int* in_sizes, int n_in,
                              void* d_out, int out_size, void* d_ws, size_t ws_size,
                              hipStream_t stream) {
    const float* x  = (const float*)d_in[0];
    const int*   er = (const int*)d_in[1];
    const int*   ec = (const int*)d_in[2];
    const float* ev = (const float*)d_in[3];
    const float* W1 = (const float*)d_in[4];
    const float* b1 = (const float*)d_in[5];
    const float* W2 = (const float*)d_in[6];
    const float* b2 = (const float*)d_in[7];
    const float* W3 = (const float*)d_in[8];
    const float* b3 = (const float*)d_in[9];
    const float* Wd = (const float*)d_in[10];
    const float* bd = (const float*)d_in[11];
    float* out = (float*)d_out;

    const int N = in_sizes[0] / NFEAT;
    const int E = in_sizes[1];

    char* w = (char*)d_ws;
    auto alloc = [&](size_t bytes) { char* p = w; w += (bytes + 255) & ~(size_t)255; return p; };
    float* C   = (float*)alloc((size_t)N * 256 * 4);
    unsigned int* C24 = (unsigned int*)alloc((size_t)N * 256 * 3);
    unsigned short* hh = (unsigned short*)alloc((size_t)N * 256 * 2);
    unsigned short* hl = (unsigned short*)alloc((size_t)N * 256 * 2);
    int* cnt  = (int*)alloc((size_t)N * 4);
    int* rp   = (int*)alloc((size_t)(N + 1) * 4);
    int* ofs  = (int*)alloc((size_t)N * 4);
    int2* ev2 = (int2*)alloc((size_t)E * 8);
    int* bsum = (int*)alloc(4096);
    unsigned short* W1h = (unsigned short*)alloc((size_t)NFEAT * H2 * 2);
    unsigned short* W1l = (unsigned short*)alloc((size_t)NFEAT * H2 * 2);
    unsigned short* W2h = (unsigned short*)alloc((size_t)H2 * H3 * 2);
    unsigned short* W2l = (unsigned short*)alloc((size_t)H2 * H3 * 2);
    unsigned short* W3h = (unsigned short*)alloc((size_t)H3 * H4 * 2);
    unsigned short* W3l = (unsigned short*)alloc((size_t)H3 * H4 * 2);

    const int nb = (N + 255) / 256;

    hipMemsetAsync(cnt, 0, (size_t)N * 4, stream);
    k_hist<<<1024, 256, 0, stream>>>(er, cnt, E);
    k_scan1<<<nb, 256, 0, stream>>>(cnt, rp, bsum, N);
    k_scan2<<<1, 512, 0, stream>>>(bsum, nb);
    k_scan3<<<nb, 256, 0, stream>>>(rp, ofs, bsum, cnt, N);
    k_scatter<<<1024, 256, 0, stream>>>(er, ec, ev, ofs, ev2, E);

    k_split_w<<<(NFEAT * H2 + 255) / 256, 256, 0, stream>>>(W1, W1h, W1l, NFEAT, H2);
    k_split_w<<<(H2 * H3 + 255) / 256, 256, 0, stream>>>(W2, W2h, W2l, H2, H3);
    k_split_w<<<(H3 * H4 + 255) / 256, 256, 0, stream>>>(W3, W3h, W3l, H3, H4);

    const int rgrid = (N + 63) / 64;
    const int sgrid = (N + 3) / 4;
    const long ngroup = (long)N * 256 / 4;
    const int pgrid = (int)((ngroup + 255) / 256);

    k_gemm1x<<<rgrid, 256, 0, stream>>>(x, W1h, W1l, C, N);
    k_pack24<<<pgrid, 256, 0, stream>>>(C, C24, ngroup);
    k_spmm256p<<<sgrid, 256, 0, stream>>>(rp, ev2, C24, b1, hh, hl, N);

    k_gemm_bt<H2, 4><<<rgrid, 256, 0, stream>>>(hh, hl, W2h, W2l, C, N);
    k_pack24<<<pgrid, 256, 0, stream>>>(C, C24, ngroup);
    k_spmm256p<<<sgrid, 256, 0, stream>>>(rp, ev2, C24, b2, hh, hl, N);

    k_gemm_bt<H3, 2><<<rgrid, 256, 0, stream>>>(hh, hl, W3h, W3l, C, N);
    k_spmm128d<<<sgrid, 256, 0, stream>>>(rp, ev2, C, b3, Wd, bd, out, N);
}